// Round 7
// baseline (92.877 us; speedup 1.0000x reference)
//
#include <hip/hip_runtime.h>
#include <hip/hip_bf16.h>
#include <math.h>

// GAT layer: B=8, N=2048, D_IN=128, D_OUT=64, fp32.
// Round 7: MEASUREMENT ROUND (round 6 fixed: nontemporal builtin needs a
// native clang ext_vector type, not HIP's float4 class). k1 + k2 are
// byte-identical to round 4 (known combined 62.3 us). gat_probe_kernel is a
// pure, tuned adj read stream -> probe_time = dur_us - 62.3.
//   H1 (read-path ceiling ~2.4 TB/s): probe ~56 us, dur ~118 us
//   H2 (stream is fast, k2 structure at fault): probe ~22 us, dur ~84 us

#define GAT_B 8
#define GAT_N 2048
#define GAT_DIN 128
#define GAT_DOUT 64
#define GAT_CAP 192   // per-row neighbor list capacity (row nnz ~42 +- 6.4)

typedef float f32x4 __attribute__((ext_vector_type(4)));

// ---------------- Probe: pure adj read stream at max MLP ----------------
// 2048 blocks x 256 thr (exactly 8 blocks/CU, fully resident, 1 generation).
// Each thread: 16 independent nontemporal 16B loads, grid-stride slabs.
// Deterministic: fixed per-thread sum order, wave reduce, 1 write per wave.
__global__ __launch_bounds__(256) void gat_probe_kernel(
    const f32x4* __restrict__ adj4, float* __restrict__ scratch) {
  const size_t tid = (size_t)blockIdx.x * 256 + threadIdx.x;
  const size_t T = (size_t)2048 * 256;   // 524288 threads
  float s = 0.f;
#pragma unroll
  for (int k = 0; k < 16; ++k) {         // 8,388,608 f32x4 total / 524288
    const f32x4 v = __builtin_nontemporal_load(&adj4[tid + (size_t)k * T]);
    s += (v.x + v.y) + (v.z + v.w);
  }
#pragma unroll
  for (int off = 32; off >= 1; off >>= 1) s += __shfl_xor(s, off);
  if ((threadIdx.x & 63) == 0)
    scratch[blockIdx.x * 4 + (threadIdx.x >> 6)] = s;
}

// ---------------- Kernel 1: wh = h @ w, s1, s2 (identical to round 4) ------
__global__ __launch_bounds__(256) void gat_wh_kernel(
    const float* __restrict__ h, const float* __restrict__ w,
    const float* __restrict__ a, float* __restrict__ wh,
    float* __restrict__ s1, float* __restrict__ s2) {
  __shared__ float w_lds[GAT_DIN * GAT_DOUT];   // 32 KB
  __shared__ float h_lds[4][GAT_DIN];           // 2 KB

  for (int t = threadIdx.x; t < (GAT_DIN * GAT_DOUT) / 4; t += 256)
    ((float4*)w_lds)[t] = ((const float4*)w)[t];

  const int lane = threadIdx.x & 63;
  const int wv = threadIdx.x >> 6;
  const float a1 = a[lane];
  const float a2 = a[GAT_DOUT + lane];

  const int ngroups = (GAT_B * GAT_N) / 4;  // 4096 groups of 4 rows
  for (int rg = blockIdx.x; rg < ngroups; rg += gridDim.x) {
    __syncthreads();
    const float4* hsrc = (const float4*)(h + (size_t)rg * 4 * GAT_DIN);
    for (int t = threadIdx.x; t < (4 * GAT_DIN) / 4; t += 256)
      ((float4*)&h_lds[0][0])[t] = hsrc[t];
    __syncthreads();

    const int row = rg * 4 + wv;
    float acc = 0.f;
#pragma unroll 16
    for (int d = 0; d < GAT_DIN; ++d)
      acc = fmaf(h_lds[wv][d], w_lds[d * GAT_DOUT + lane], acc);

    wh[(size_t)row * GAT_DOUT + lane] = acc;

    float t1 = acc * a1, t2 = acc * a2;
#pragma unroll
    for (int off = 32; off >= 1; off >>= 1) {
      t1 += __shfl_xor(t1, off);
      t2 += __shfl_xor(t2, off);
    }
    if (lane == 0) { s1[row] = t1; s2[row] = t2; }
  }
}

// ---------------- Kernel 2: wave-per-row (identical to round 4) -------------
__global__ __launch_bounds__(256) void gat_row_kernel(
    const float* __restrict__ adj, const float* __restrict__ wh,
    const float* __restrict__ s1, const float* __restrict__ s2,
    float* __restrict__ out) {
  __shared__ float s2_lds[GAT_N];                 // 8 KB
  __shared__ float sc_l[4][GAT_CAP];              // 3 KB
  __shared__ unsigned short idx_l[4][GAT_CAP];    // 1.5 KB

  const int lane = threadIdx.x & 63;
  const int wv = threadIdx.x >> 6;
  const int b = blockIdx.x >> 9;                  // batch
  const int g = blockIdx.x & 511;
  const int row = (b << 11) + g * 4 + wv;

  const float* adj_row = adj + (size_t)row * GAT_N;
  const float* whb = wh + ((size_t)b << 11) * GAT_DOUT;

  float4 av[8];
#pragma unroll
  for (int u = 0; u < 8; ++u)
    av[u] = *(const float4*)(adj_row + u * 256 + lane * 4);

  {
    const float4* src = (const float4*)(s2 + ((size_t)b << 11));
    float4* dst = (float4*)s2_lds;
    dst[threadIdx.x] = src[threadIdx.x];
    dst[threadIdx.x + 256] = src[threadIdx.x + 256];
  }
  const float s1i = s1[row];
  __syncthreads();

  int base = 0;
  float cmax = -1e30f;
  float* my_sc = sc_l[wv];
  unsigned short* my_idx = idx_l[wv];
#pragma unroll
  for (int u = 0; u < 8; ++u) {
#pragma unroll
    for (int comp = 0; comp < 4; ++comp) {
      const float a_c = (comp == 0) ? av[u].x : (comp == 1) ? av[u].y
                       : (comp == 2) ? av[u].z : av[u].w;
      const bool pred = a_c > 0.f;
      const unsigned long long msk = __ballot(pred);
      if (msk) {  // wave-uniform
        const int prefix = __builtin_amdgcn_mbcnt_hi(
            (unsigned)(msk >> 32),
            __builtin_amdgcn_mbcnt_lo((unsigned)msk, 0u));
        if (pred) {
          const int p = base + prefix;
          if (p < GAT_CAP) {
            const int j = u * 256 + lane * 4 + comp;
            float sc = s1i + s2_lds[j];
            sc = (sc >= 0.f) ? sc : 0.2f * sc;   // LeakyReLU(0.2)
            my_sc[p] = sc;
            my_idx[p] = (unsigned short)j;
            cmax = fmaxf(cmax, sc);
          }
        }
        base += (int)__popcll(msk);
      }
    }
  }
  base = min(base, GAT_CAP);

#pragma unroll
  for (int off = 32; off >= 1; off >>= 1)
    cmax = fmaxf(cmax, __shfl_xor(cmax, off));
  const float m = cmax;

  float l0 = 0.f, l1 = 0.f, acc0 = 0.f, acc1 = 0.f;
  int t = 0;
  for (; t + 2 <= base; t += 2) {
    const float e0 = __expf(my_sc[t] - m);
    const float e1 = __expf(my_sc[t + 1] - m);
    const int j0 = my_idx[t];
    const int j1 = my_idx[t + 1];
    l0 += e0;
    l1 += e1;
    acc0 = fmaf(e0, whb[(size_t)j0 * GAT_DOUT + lane], acc0);
    acc1 = fmaf(e1, whb[(size_t)j1 * GAT_DOUT + lane], acc1);
  }
  if (t < base) {
    const float e0 = __expf(my_sc[t] - m);
    const int j0 = my_idx[t];
    l0 += e0;
    acc0 = fmaf(e0, whb[(size_t)j0 * GAT_DOUT + lane], acc0);
  }

  out[(size_t)row * GAT_DOUT + lane] = (acc0 + acc1) / (l0 + l1);
}

extern "C" void kernel_launch(void* const* d_in, const int* in_sizes, int n_in,
                              void* d_out, int out_size, void* d_ws, size_t ws_size,
                              hipStream_t stream) {
  const float* h   = (const float*)d_in[0];  // (8, 2048, 128)
  const float* adj = (const float*)d_in[1];  // (8, 2048, 2048)
  const float* w   = (const float*)d_in[2];  // (128, 64)
  const float* a   = (const float*)d_in[3];  // (128, 1)
  float* out = (float*)d_out;                // (8, 2048, 64)

  const size_t rows = (size_t)GAT_B * GAT_N;           // 16384
  float* wh = (float*)d_ws;                            // rows*64 floats = 4 MB
  float* s1 = wh + rows * GAT_DOUT;                    // 64 KB
  float* s2 = s1 + rows;                               // 64 KB
  float* probe_scratch = s2 + rows;                    // 32 KB (probe output)

  // Probe first: pure adj read stream (timing isolated by dur_us subtraction).
  gat_probe_kernel<<<2048, 256, 0, stream>>>((const f32x4*)adj, probe_scratch);

  gat_wh_kernel<<<1024, 256, 0, stream>>>(h, w, a, wh, s1, s2);
  gat_row_kernel<<<GAT_B * (GAT_N / 4), 256, 0, stream>>>(adj, wh, s1, s2, out);
}

// Round 8
// 69.914 us; speedup vs baseline: 1.3284x; 1.3284x over previous
//
#include <hip/hip_runtime.h>
#include <hip/hip_bf16.h>
#include <math.h>

// GAT layer: B=8, N=2048, D_IN=128, D_OUT=64, fp32.
// Round 8: convoy-effect fix. Probe (R7) showed pure adj stream = ~30.6us
// (~4.6 TB/s), k2 has ~25us slack. Theory: waves burst-load then compute with
// zero loads outstanding; phases align across the GPU -> HBM duty ~50%.
// Fix: each wave owns 4 rows and prefetches row i+1's adj during row i's
// compute. 1024 blocks x 4 waves, all resident (launch_bounds 256,4).

#define GAT_B 8
#define GAT_N 2048
#define GAT_DIN 128
#define GAT_DOUT 64
#define GAT_CAP 192   // per-row neighbor list capacity (row nnz ~42 +- 6.4)

// ---------------- Kernel 1: wh = h @ w, s1, s2 ----------------
__global__ __launch_bounds__(256) void gat_wh_kernel(
    const float* __restrict__ h, const float* __restrict__ w,
    const float* __restrict__ a, float* __restrict__ wh,
    float* __restrict__ s1, float* __restrict__ s2) {
  __shared__ float w_lds[GAT_DIN * GAT_DOUT];   // 32 KB
  __shared__ float h_lds[4][GAT_DIN];           // 2 KB

  for (int t = threadIdx.x; t < (GAT_DIN * GAT_DOUT) / 4; t += 256)
    ((float4*)w_lds)[t] = ((const float4*)w)[t];

  const int lane = threadIdx.x & 63;
  const int wv = threadIdx.x >> 6;
  const float a1 = a[lane];
  const float a2 = a[GAT_DOUT + lane];

  const int ngroups = (GAT_B * GAT_N) / 4;  // 4096 groups of 4 rows
  for (int rg = blockIdx.x; rg < ngroups; rg += gridDim.x) {
    __syncthreads();
    const float4* hsrc = (const float4*)(h + (size_t)rg * 4 * GAT_DIN);
    for (int t = threadIdx.x; t < (4 * GAT_DIN) / 4; t += 256)
      ((float4*)&h_lds[0][0])[t] = hsrc[t];
    __syncthreads();

    const int row = rg * 4 + wv;
    float acc = 0.f;
#pragma unroll 16
    for (int d = 0; d < GAT_DIN; ++d)
      acc = fmaf(h_lds[wv][d], w_lds[d * GAT_DOUT + lane], acc);

    wh[(size_t)row * GAT_DOUT + lane] = acc;

    float t1 = acc * a1, t2 = acc * a2;
#pragma unroll
    for (int off = 32; off >= 1; off >>= 1) {
      t1 += __shfl_xor(t1, off);
      t2 += __shfl_xor(t2, off);
    }
    if (lane == 0) { s1[row] = t1; s2[row] = t2; }
  }
}

// ---------------- Kernel 2: pipelined wave-per-row -------------------------
// 1024 blocks x 256 thr, all resident. Block -> batch b = blockIdx>>7,
// group g = blockIdx&127. Wave wv handles rows b*2048 + g*16 + wv*4 + i,
// i = 0..3, prefetching row i+1's adj while processing row i.
__global__ __launch_bounds__(256, 4) void gat_row_kernel(
    const float* __restrict__ adj, const float* __restrict__ wh,
    const float* __restrict__ s1, const float* __restrict__ s2,
    float* __restrict__ out) {
  __shared__ float s2_lds[GAT_N];                 // 8 KB
  __shared__ float sc_l[4][GAT_CAP];              // 3 KB
  __shared__ unsigned short idx_l[4][GAT_CAP];    // 1.5 KB

  const int lane = threadIdx.x & 63;
  const int wv = threadIdx.x >> 6;
  const int b = blockIdx.x >> 7;                  // batch
  const int g = blockIdx.x & 127;
  const int row0 = (b << 11) + g * 16 + wv * 4;

  const float* whb = wh + ((size_t)b << 11) * GAT_DOUT;
  float* my_sc = sc_l[wv];
  unsigned short* my_idx = idx_l[wv];

  // Prefetch row0's adj (in flight across the s2 stage + first compaction).
  float4 avA[8], avB[8];
  {
    const float* ar = adj + (size_t)row0 * GAT_N;
#pragma unroll
    for (int u = 0; u < 8; ++u)
      avA[u] = *(const float4*)(ar + u * 256 + lane * 4);
  }

  // Stage this batch's s2 row (8 KB) once per block.
  {
    const float4* src = (const float4*)(s2 + ((size_t)b << 11));
    float4* dst = (float4*)s2_lds;
    dst[threadIdx.x] = src[threadIdx.x];
    dst[threadIdx.x + 256] = src[threadIdx.x + 256];
  }
  __syncthreads();

#pragma unroll
  for (int i = 0; i < 4; ++i) {
    const float4* av = (i & 1) ? avB : avA;   // compile-time after unroll
    // Issue next row's prefetch BEFORE processing current row: these 8
    // independent 1KB loads stay in flight under the compaction below.
    if (i < 3) {
      float4* nxt = (i & 1) ? avA : avB;
      const float* ar = adj + (size_t)(row0 + i + 1) * GAT_N;
#pragma unroll
      for (int u = 0; u < 8; ++u)
        nxt[u] = *(const float4*)(ar + u * 256 + lane * 4);
    }

    const int row = row0 + i;
    const float s1i = s1[row];

    // Ballot+mbcnt compaction of nonzero (j, score) into this wave's list.
    int base = 0;
    float cmax = -1e30f;
#pragma unroll
    for (int u = 0; u < 8; ++u) {
#pragma unroll
      for (int comp = 0; comp < 4; ++comp) {
        const float a_c = (comp == 0) ? av[u].x : (comp == 1) ? av[u].y
                         : (comp == 2) ? av[u].z : av[u].w;
        const bool pred = a_c > 0.f;
        const unsigned long long msk = __ballot(pred);
        if (msk) {  // wave-uniform
          const int prefix = __builtin_amdgcn_mbcnt_hi(
              (unsigned)(msk >> 32),
              __builtin_amdgcn_mbcnt_lo((unsigned)msk, 0u));
          if (pred) {
            const int p = base + prefix;
            if (p < GAT_CAP) {   // clamp: no OOB even for absurd densities
              const int j = u * 256 + lane * 4 + comp;
              float sc = s1i + s2_lds[j];
              sc = (sc >= 0.f) ? sc : 0.2f * sc;   // LeakyReLU(0.2)
              my_sc[p] = sc;
              my_idx[p] = (unsigned short)j;
              cmax = fmaxf(cmax, sc);
            }
          }
          base += (int)__popcll(msk);
        }
      }
    }
    base = min(base, GAT_CAP);

    // Row max (wave owns the whole row; self-loop => base >= 1).
#pragma unroll
    for (int off = 32; off >= 1; off >>= 1)
      cmax = fmaxf(cmax, __shfl_xor(cmax, off));
    const float m = cmax;

    // Lane-parallel exp; overwrite score list with weights; wave-sum.
    float lsum = 0.f;
#pragma unroll
    for (int k = 0; k < 3; ++k) {
      const int t = k * 64 + lane;
      if (t < base) {
        const float e = __expf(my_sc[t] - m);
        my_sc[t] = e;
        lsum += e;
      }
    }
#pragma unroll
    for (int off = 32; off >= 1; off >>= 1)
      lsum += __shfl_xor(lsum, off);
    const float inv = 1.f / lsum;

    // Weighted gather, 4 accumulators for MLP/ILP.
    float A0 = 0.f, A1 = 0.f, A2 = 0.f, A3 = 0.f;
    int t = 0;
    for (; t + 4 <= base; t += 4) {
      const float w0 = my_sc[t],     w1 = my_sc[t + 1];
      const float w2 = my_sc[t + 2], w3 = my_sc[t + 3];
      const int j0 = my_idx[t],      j1 = my_idx[t + 1];
      const int j2 = my_idx[t + 2],  j3 = my_idx[t + 3];
      A0 = fmaf(w0, whb[(size_t)j0 * GAT_DOUT + lane], A0);
      A1 = fmaf(w1, whb[(size_t)j1 * GAT_DOUT + lane], A1);
      A2 = fmaf(w2, whb[(size_t)j2 * GAT_DOUT + lane], A2);
      A3 = fmaf(w3, whb[(size_t)j3 * GAT_DOUT + lane], A3);
    }
    for (; t < base; ++t) {
      A0 = fmaf(my_sc[t], whb[(size_t)my_idx[t] * GAT_DOUT + lane], A0);
    }

    out[(size_t)row * GAT_DOUT + lane] = ((A0 + A1) + (A2 + A3)) * inv;
  }
}

extern "C" void kernel_launch(void* const* d_in, const int* in_sizes, int n_in,
                              void* d_out, int out_size, void* d_ws, size_t ws_size,
                              hipStream_t stream) {
  const float* h   = (const float*)d_in[0];  // (8, 2048, 128)
  const float* adj = (const float*)d_in[1];  // (8, 2048, 2048)
  const float* w   = (const float*)d_in[2];  // (128, 64)
  const float* a   = (const float*)d_in[3];  // (128, 1)
  float* out = (float*)d_out;                // (8, 2048, 64)

  const size_t rows = (size_t)GAT_B * GAT_N;           // 16384
  float* wh = (float*)d_ws;                            // rows*64 floats = 4 MB
  float* s1 = wh + rows * GAT_DOUT;                    // 64 KB
  float* s2 = s1 + rows;                               // 64 KB

  gat_wh_kernel<<<1024, 256, 0, stream>>>(h, w, a, wh, s1, s2);
  // 1024 blocks = 8 batches x 128 groups; 4 waves/block, 4 rows/wave.
  gat_row_kernel<<<1024, 256, 0, stream>>>(adj, wh, s1, s2, out);
}

// Round 9
// 62.441 us; speedup vs baseline: 1.4874x; 1.1197x over previous
//
#include <hip/hip_runtime.h>
#include <hip/hip_bf16.h>
#include <math.h>

// GAT layer: B=8, N=2048, D_IN=128, D_OUT=64, fp32.
// Round 9: SPLIT AT THE BITMASK. Evidence: pure adj stream = 30.6us (R7),
// stream+compaction (no gathers) = ~57us (R5 kA), gather-only = ~7us (R5 kB).
// => compaction machinery in the stream kernel costs +26us. Fix: kernel S
// streams adj -> 4MB bitmask (ballot only, no LDS/exp/serial chains, probe-
// like); kernel G does bit-expand + softmax + gather against L2-resident data.

#define GAT_B 8
#define GAT_N 2048
#define GAT_DIN 128
#define GAT_DOUT 64
#define GAT_CAP 192   // per-row list capacity (row nnz ~42 +- 6.4; clamped)

// ---------------- Kernel 1: wh = h @ w, s1, s2 ----------------
__global__ __launch_bounds__(256) void gat_wh_kernel(
    const float* __restrict__ h, const float* __restrict__ w,
    const float* __restrict__ a, float* __restrict__ wh,
    float* __restrict__ s1, float* __restrict__ s2) {
  __shared__ float w_lds[GAT_DIN * GAT_DOUT];   // 32 KB
  __shared__ float h_lds[4][GAT_DIN];           // 2 KB

  for (int t = threadIdx.x; t < (GAT_DIN * GAT_DOUT) / 4; t += 256)
    ((float4*)w_lds)[t] = ((const float4*)w)[t];

  const int lane = threadIdx.x & 63;
  const int wv = threadIdx.x >> 6;
  const float a1 = a[lane];
  const float a2 = a[GAT_DOUT + lane];

  const int ngroups = (GAT_B * GAT_N) / 4;  // 4096 groups of 4 rows
  for (int rg = blockIdx.x; rg < ngroups; rg += gridDim.x) {
    __syncthreads();
    const float4* hsrc = (const float4*)(h + (size_t)rg * 4 * GAT_DIN);
    for (int t = threadIdx.x; t < (4 * GAT_DIN) / 4; t += 256)
      ((float4*)&h_lds[0][0])[t] = hsrc[t];
    __syncthreads();

    const int row = rg * 4 + wv;
    float acc = 0.f;
#pragma unroll 16
    for (int d = 0; d < GAT_DIN; ++d)
      acc = fmaf(h_lds[wv][d], w_lds[d * GAT_DOUT + lane], acc);

    wh[(size_t)row * GAT_DOUT + lane] = acc;

    float t1 = acc * a1, t2 = acc * a2;
#pragma unroll
    for (int off = 32; off >= 1; off >>= 1) {
      t1 += __shfl_xor(t1, off);
      t2 += __shfl_xor(t2, off);
    }
    if (lane == 0) { s1[row] = t1; s2[row] = t2; }
  }
}

// ---------------- Kernel S: adj stream -> bitmask (probe-like) --------------
// bm layout per row: 32 u64 words, word w = u*4+comp; u64 bit i -> col
// u*256 + i*4 + comp. 2048 blocks x 4 waves, 2 rows/wave, zero LDS.
__global__ __launch_bounds__(256) void gat_bits_kernel(
    const float* __restrict__ adj, unsigned long long* __restrict__ bm) {
  const int lane = threadIdx.x & 63;
  const int wid = blockIdx.x * 4 + (threadIdx.x >> 6);  // 0..8191
#pragma unroll
  for (int r = 0; r < 2; ++r) {
    const int row = wid * 2 + r;
    const float* ar = adj + (size_t)row * GAT_N;
    unsigned long long* bmrow = bm + (size_t)row * 32;
#pragma unroll
    for (int u = 0; u < 8; ++u) {
      const float4 av = *(const float4*)(ar + u * 256 + lane * 4);
      const unsigned long long b0 = __ballot(av.x > 0.f);
      const unsigned long long b1 = __ballot(av.y > 0.f);
      const unsigned long long b2 = __ballot(av.z > 0.f);
      const unsigned long long b3 = __ballot(av.w > 0.f);
      if (lane < 4) {
        const unsigned long long v = (lane == 0) ? b0 : (lane == 1) ? b1
                                    : (lane == 2) ? b2 : b3;
        bmrow[u * 4 + lane] = v;
      }
    }
  }
}

// ---------------- Kernel G: bit-expand + softmax + gather -------------------
// Wave per row; lane i owns u32 word i of the row's bitmask:
//   w=i>>1, h=i&1, u=i>>3, comp=(i>>1)&3; bit j -> col u*256+h*128+j*4+comp.
__global__ __launch_bounds__(256) void gat_agg_kernel(
    const unsigned int* __restrict__ bm32, const float* __restrict__ wh,
    const float* __restrict__ s1, const float* __restrict__ s2,
    float* __restrict__ out) {
  __shared__ float s2_lds[GAT_N];                 // 8 KB
  __shared__ float2 list_l[4][GAT_CAP];           // 6 KB (x=score/weight, y=col)

  const int lane = threadIdx.x & 63;
  const int wv = threadIdx.x >> 6;
  const int b = blockIdx.x >> 9;                  // batch
  const int g = blockIdx.x & 511;
  const int row = (b << 11) + g * 4 + wv;

  // Stage this batch's s2 row (8 KB) once per block.
  {
    const float4* src = (const float4*)(s2 + ((size_t)b << 11));
    float4* dst = (float4*)s2_lds;
    dst[threadIdx.x] = src[threadIdx.x];
    dst[threadIdx.x + 256] = src[threadIdx.x + 256];
  }
  const float s1i = s1[row];
  const float* whb = wh + ((size_t)b << 11) * GAT_DOUT;
  __syncthreads();

  // Lane's bitmask word (coalesced 256B row read, L2-resident).
  unsigned int mw = bm32[(size_t)row * 64 + lane];
  const int cnt = __popc(mw);

  // Inclusive wave prefix-scan of counts -> exclusive position.
  int pos = cnt;
#pragma unroll
  for (int off = 1; off < 64; off <<= 1) {
    const int v = __shfl_up(pos, off);
    pos += (lane >= off) ? v : 0;
  }
  const int total = __shfl(pos, 63);
  pos -= cnt;                                     // exclusive prefix

  // Decode constants for this lane's word.
  const int colbase = (lane >> 3) * 256 + (lane & 1) * 128 + ((lane >> 1) & 3);

  // Per-lane bit expansion: write (score, col) into the wave list.
  float lmax = -1e30f;
  float2* mylist = list_l[wv];
  int p = pos;
  while (mw) {
    const int j = __builtin_ctz(mw);
    mw &= mw - 1;
    const int col = colbase + 4 * j;
    float sc = s1i + s2_lds[col];
    sc = (sc >= 0.f) ? sc : 0.2f * sc;            // LeakyReLU(0.2)
    if (p < GAT_CAP) mylist[p] = make_float2(sc, __uint_as_float((unsigned)col));
    lmax = fmaxf(lmax, sc);
    ++p;
  }
  const int base = min(total, GAT_CAP);

  // Row max (self-loop guarantees base >= 1).
#pragma unroll
  for (int off = 32; off >= 1; off >>= 1)
    lmax = fmaxf(lmax, __shfl_xor(lmax, off));
  const float m = lmax;

  // Lane-parallel exp; write weights back; wave sum.
  float lsum = 0.f;
#pragma unroll
  for (int k = 0; k < 3; ++k) {
    const int t = k * 64 + lane;
    if (t < base) {
      const float e = __expf(mylist[t].x - m);
      mylist[t].x = e;
      lsum += e;
    }
  }
#pragma unroll
  for (int off = 32; off >= 1; off >>= 1)
    lsum += __shfl_xor(lsum, off);
  const float inv = 1.f / lsum;

  // Weighted gather, 4 accumulators for MLP/ILP.
  float A0 = 0.f, A1 = 0.f, A2 = 0.f, A3 = 0.f;
  int t = 0;
  for (; t + 4 <= base; t += 4) {
    const float2 e0 = mylist[t],     e1 = mylist[t + 1];
    const float2 e2 = mylist[t + 2], e3 = mylist[t + 3];
    const int j0 = (int)__float_as_uint(e0.y);
    const int j1 = (int)__float_as_uint(e1.y);
    const int j2 = (int)__float_as_uint(e2.y);
    const int j3 = (int)__float_as_uint(e3.y);
    A0 = fmaf(e0.x, whb[(size_t)j0 * GAT_DOUT + lane], A0);
    A1 = fmaf(e1.x, whb[(size_t)j1 * GAT_DOUT + lane], A1);
    A2 = fmaf(e2.x, whb[(size_t)j2 * GAT_DOUT + lane], A2);
    A3 = fmaf(e3.x, whb[(size_t)j3 * GAT_DOUT + lane], A3);
  }
  for (; t < base; ++t) {
    const float2 e0 = mylist[t];
    A0 = fmaf(e0.x, whb[(size_t)(int)__float_as_uint(e0.y) * GAT_DOUT + lane], A0);
  }

  out[(size_t)row * GAT_DOUT + lane] = ((A0 + A1) + (A2 + A3)) * inv;
}

extern "C" void kernel_launch(void* const* d_in, const int* in_sizes, int n_in,
                              void* d_out, int out_size, void* d_ws, size_t ws_size,
                              hipStream_t stream) {
  const float* h   = (const float*)d_in[0];  // (8, 2048, 128)
  const float* adj = (const float*)d_in[1];  // (8, 2048, 2048)
  const float* w   = (const float*)d_in[2];  // (128, 64)
  const float* a   = (const float*)d_in[3];  // (128, 1)
  float* out = (float*)d_out;                // (8, 2048, 64)

  const size_t rows = (size_t)GAT_B * GAT_N;           // 16384
  float* wh = (float*)d_ws;                            // rows*64 floats = 4 MB
  float* s1 = wh + rows * GAT_DOUT;                    // 64 KB
  float* s2 = s1 + rows;                               // 64 KB
  unsigned long long* bm = (unsigned long long*)(s2 + rows);  // rows*32*8B = 4 MB

  // S first (independent of k1), then k1, then G (needs both).
  gat_bits_kernel<<<2048, 256, 0, stream>>>(adj, bm);
  gat_wh_kernel<<<1024, 256, 0, stream>>>(h, w, a, wh, s1, s2);
  gat_agg_kernel<<<GAT_B * (GAT_N / 4), 256, 0, stream>>>(
      (const unsigned int*)bm, wh, s1, s2, out);
}